// Round 2
// baseline (237.295 us; speedup 1.0000x reference)
//
#include <hip/hip_runtime.h>

#define LN_EPS 1e-5f

// ---------------------------------------------------------------------------
// Wave (64-lane) sum.
// ---------------------------------------------------------------------------
__device__ __forceinline__ float wave_sum(float v) {
    #pragma unroll
    for (int o = 32; o; o >>= 1) v += __shfl_down(v, o);
    return v;
}

// 256-thread block sum (4 waves). sh: 4 floats. Result broadcast to all.
// Safe to call repeatedly with the same sh (trailing sync included).
__device__ __forceinline__ float block_sum_256(float v, float* sh) {
    int lane = threadIdx.x & 63, w = threadIdx.x >> 6;
    v = wave_sum(v);
    if (lane == 0) sh[w] = v;
    __syncthreads();
    float r = sh[0] + sh[1] + sh[2] + sh[3];
    __syncthreads();
    return r;
}

// 1024-thread block sum (16 waves). sh: 16 floats.
__device__ __forceinline__ float block_sum_1024(float v, float* sh) {
    int lane = threadIdx.x & 63, w = threadIdx.x >> 6;
    v = wave_sum(v);
    if (lane == 0) sh[w] = v;
    __syncthreads();
    if (w == 0) {
        float s = (lane < 16) ? sh[lane] : 0.f;
        #pragma unroll
        for (int o = 8; o; o >>= 1) s += __shfl_down(s, o);
        if (lane == 0) sh[0] = s;
    }
    __syncthreads();
    float r = sh[0];
    __syncthreads();
    return r;
}

// ---------------------------------------------------------------------------
// K1: t1 = W_I_H1 @ input (4096x2048), t2 = W_H2_H1 @ h2_prev (4096x4096).
// 4 rows/block (one per wave), x staged in LDS. Per-block (sum,sumsq) partial
// of the 4 produced row values -> p1/p2 (deterministic, no atomics).
// grid = 1024 + 1024 = 2048 blocks of 256.
// ---------------------------------------------------------------------------
__global__ __launch_bounds__(256) void k1(
        const float* __restrict__ W_I_H1, const float* __restrict__ x_in,
        const float* __restrict__ W_H2_H1, const float* __restrict__ h2_prev,
        float* __restrict__ t1, float* __restrict__ t2,
        float2* __restrict__ p1, float2* __restrict__ p2) {
    extern __shared__ float xs[];
    __shared__ float shy[4];
    const float* W; const float* x; float* y; float2* p; int C; int blk;
    if ((int)blockIdx.x < 1024) {
        W = W_I_H1;  x = x_in;    y = t1; p = p1; C = 2048; blk = blockIdx.x;
    } else {
        W = W_H2_H1; x = h2_prev; y = t2; p = p2; C = 4096; blk = blockIdx.x - 1024;
    }
    int n4 = C >> 2;
    float4* xs4 = (float4*)xs;
    for (int i = threadIdx.x; i < n4; i += 256)
        xs4[i] = ((const float4*)x)[i];
    __syncthreads();

    int wave = threadIdx.x >> 6, lane = threadIdx.x & 63;
    int row = blk * 4 + wave;
    const float4* Wr = (const float4*)(W + (size_t)row * C);
    float acc = 0.f;
    #pragma unroll 4
    for (int i = lane; i < n4; i += 64) {
        float4 w = Wr[i], v = xs4[i];
        acc += w.x * v.x + w.y * v.y + w.z * v.z + w.w * v.w;
    }
    acc = wave_sum(acc);
    if (lane == 0) { y[row] = acc; shy[wave] = acc; }
    __syncthreads();
    if (threadIdx.x == 0) {
        float s = 0.f, q = 0.f;
        #pragma unroll
        for (int i = 0; i < 4; i++) { float v = shy[i]; s += v; q += v * v; }
        p[blk] = make_float2(s, q);
    }
}

// ---------------------------------------------------------------------------
// K2: prologue reduces p1/p2 -> LN stats of t1,t2; builds
// h1 = tanh(LN(t1)) + tanh(LN(t2)) directly into LDS. Then
// t3 = W_H1_H2 @ h1 (4096 rows), t4 = W_H1_O @ h1 (1024 rows), partials
// p3/p4. grid = 1024 + 256 = 1280 blocks of 256.
// ---------------------------------------------------------------------------
__global__ __launch_bounds__(256) void k2(
        const float* __restrict__ t1, const float* __restrict__ t2,
        const float2* __restrict__ p1, const float2* __restrict__ p2,
        const float* __restrict__ g, const float* __restrict__ b,
        const float* __restrict__ W_H1_H2, const float* __restrict__ W_H1_O,
        float* __restrict__ t3, float* __restrict__ t4,
        float2* __restrict__ p3, float2* __restrict__ p4) {
    extern __shared__ float xs[];          // 4096 floats: h1
    __shared__ float shr[4];
    __shared__ float shy[4];

    float s1 = 0.f, q1 = 0.f, s2 = 0.f, q2 = 0.f;
    for (int i = threadIdx.x; i < 1024; i += 256) {
        float2 a = p1[i]; s1 += a.x; q1 += a.y;
        float2 c = p2[i]; s2 += c.x; q2 += c.y;
    }
    s1 = block_sum_256(s1, shr); q1 = block_sum_256(q1, shr);
    s2 = block_sum_256(s2, shr); q2 = block_sum_256(q2, shr);
    const float invN = 1.f / 4096.f;
    float m1 = s1 * invN, r1 = rsqrtf(fmaxf(q1 * invN - m1 * m1, 0.f) + LN_EPS);
    float m2 = s2 * invN, r2 = rsqrtf(fmaxf(q2 * invN - m2 * m2, 0.f) + LN_EPS);

    float4* xs4 = (float4*)xs;
    for (int i = threadIdx.x; i < 1024; i += 256) {
        float4 a = ((const float4*)t1)[i], c = ((const float4*)t2)[i];
        float4 gv = ((const float4*)g)[i], bv = ((const float4*)b)[i];
        float4 o;
        o.x = tanhf((a.x - m1) * r1 * gv.x + bv.x) + tanhf((c.x - m2) * r2 * gv.x + bv.x);
        o.y = tanhf((a.y - m1) * r1 * gv.y + bv.y) + tanhf((c.y - m2) * r2 * gv.y + bv.y);
        o.z = tanhf((a.z - m1) * r1 * gv.z + bv.z) + tanhf((c.z - m2) * r2 * gv.z + bv.z);
        o.w = tanhf((a.w - m1) * r1 * gv.w + bv.w) + tanhf((c.w - m2) * r2 * gv.w + bv.w);
        xs4[i] = o;
    }
    __syncthreads();

    const float* W; float* y; float2* p; int blk;
    if ((int)blockIdx.x < 1024) { W = W_H1_H2; y = t3; p = p3; blk = blockIdx.x; }
    else                        { W = W_H1_O;  y = t4; p = p4; blk = blockIdx.x - 1024; }
    int wave = threadIdx.x >> 6, lane = threadIdx.x & 63;
    int row = blk * 4 + wave;
    const float4* Wr = (const float4*)(W + (size_t)row * 4096);
    float acc = 0.f;
    #pragma unroll 4
    for (int i = lane; i < 1024; i += 64) {
        float4 w = Wr[i], v = xs4[i];
        acc += w.x * v.x + w.y * v.y + w.z * v.z + w.w * v.w;
    }
    acc = wave_sum(acc);
    if (lane == 0) { y[row] = acc; shy[wave] = acc; }
    __syncthreads();
    if (threadIdx.x == 0) {
        float s = 0.f, q = 0.f;
        #pragma unroll
        for (int i = 0; i < 4; i++) { float v = shy[i]; s += v; q += v * v; }
        p[blk] = make_float2(s, q);
    }
}

// ---------------------------------------------------------------------------
// K3: prologue reduces p3 -> LN stats of t3; h2 = tanh(LN(t3)) into LDS.
// t5 = W_H2_O @ h2 (1024 rows), partials p5. grid = 256 blocks of 256.
// ---------------------------------------------------------------------------
__global__ __launch_bounds__(256) void k3(
        const float* __restrict__ t3, const float2* __restrict__ p3,
        const float* __restrict__ g, const float* __restrict__ b,
        const float* __restrict__ W_H2_O,
        float* __restrict__ t5, float2* __restrict__ p5) {
    extern __shared__ float xs[];
    __shared__ float shr[4];
    __shared__ float shy[4];

    float s3 = 0.f, q3 = 0.f;
    for (int i = threadIdx.x; i < 1024; i += 256) {
        float2 a = p3[i]; s3 += a.x; q3 += a.y;
    }
    s3 = block_sum_256(s3, shr); q3 = block_sum_256(q3, shr);
    const float invN = 1.f / 4096.f;
    float m3 = s3 * invN, r3 = rsqrtf(fmaxf(q3 * invN - m3 * m3, 0.f) + LN_EPS);

    float4* xs4 = (float4*)xs;
    for (int i = threadIdx.x; i < 1024; i += 256) {
        float4 a = ((const float4*)t3)[i];
        float4 gv = ((const float4*)g)[i], bv = ((const float4*)b)[i];
        float4 o;
        o.x = tanhf((a.x - m3) * r3 * gv.x + bv.x);
        o.y = tanhf((a.y - m3) * r3 * gv.y + bv.y);
        o.z = tanhf((a.z - m3) * r3 * gv.z + bv.z);
        o.w = tanhf((a.w - m3) * r3 * gv.w + bv.w);
        xs4[i] = o;
    }
    __syncthreads();

    int wave = threadIdx.x >> 6, lane = threadIdx.x & 63;
    int row = blockIdx.x * 4 + wave;
    const float4* Wr = (const float4*)(W_H2_O + (size_t)row * 4096);
    float acc = 0.f;
    #pragma unroll 4
    for (int i = lane; i < 1024; i += 64) {
        float4 w = Wr[i], v = xs4[i];
        acc += w.x * v.x + w.y * v.y + w.z * v.z + w.w * v.w;
    }
    acc = wave_sum(acc);
    if (lane == 0) { t5[row] = acc; shy[wave] = acc; }
    __syncthreads();
    if (threadIdx.x == 0) {
        float s = 0.f, q = 0.f;
        #pragma unroll
        for (int i = 0; i < 4; i++) { float v = shy[i]; s += v; q += v * v; }
        p5[blockIdx.x] = make_float2(s, q);
    }
}

// ---------------------------------------------------------------------------
// K4: out = tanh(LN(tanh(LN(t4)) + tanh(LN(t5)))). N = 1024, one block.
// t4/t5 stats come from partials p4/p5; only the combined vector needs an
// in-block reduction.
// ---------------------------------------------------------------------------
__global__ __launch_bounds__(1024) void k4(
        const float* __restrict__ t4, const float* __restrict__ t5,
        const float2* __restrict__ p4, const float2* __restrict__ p5,
        const float* __restrict__ g, const float* __restrict__ b,
        float* __restrict__ out) {
    __shared__ float sh[16];
    int tid = threadIdx.x;
    float a4 = 0.f, c4 = 0.f, a5 = 0.f, c5 = 0.f;
    if (tid < 256) {
        float2 v = p4[tid]; a4 = v.x; c4 = v.y;
        float2 w = p5[tid]; a5 = w.x; c5 = w.y;
    }
    float s4 = block_sum_1024(a4, sh), q4 = block_sum_1024(c4, sh);
    float s5 = block_sum_1024(a5, sh), q5 = block_sum_1024(c5, sh);
    const float invN = 1.f / 1024.f;
    float m4 = s4 * invN, r4 = rsqrtf(fmaxf(q4 * invN - m4 * m4, 0.f) + LN_EPS);
    float m5 = s5 * invN, r5 = rsqrtf(fmaxf(q5 * invN - m5 * m5, 0.f) + LN_EPS);

    float gi = g[tid], bi = b[tid];
    float o = tanhf((t4[tid] - m4) * r4 * gi + bi)
            + tanhf((t5[tid] - m5) * r5 * gi + bi);

    float s = block_sum_1024(o, sh), q = block_sum_1024(o * o, sh);
    float m = s * invN, r = rsqrtf(fmaxf(q * invN - m * m, 0.f) + LN_EPS);
    out[tid] = tanhf((o - m) * r * gi + bi);
}

extern "C" void kernel_launch(void* const* d_in, const int* in_sizes, int n_in,
                              void* d_out, int out_size, void* d_ws, size_t ws_size,
                              hipStream_t stream) {
    const float* input_raw = (const float*)d_in[0];
    const float* h2_prev   = (const float*)d_in[1];
    const float* W_I_H1    = (const float*)d_in[2];
    const float* W_H2_H1   = (const float*)d_in[3];
    const float* W_H1_H2   = (const float*)d_in[4];
    const float* W_H1_O    = (const float*)d_in[5];
    const float* W_H2_O    = (const float*)d_in[6];
    const float* g_H1 = (const float*)d_in[7],  *b_H1 = (const float*)d_in[8];
    const float* g_H2 = (const float*)d_in[9],  *b_H2 = (const float*)d_in[10];
    const float* g_O  = (const float*)d_in[11], *b_O  = (const float*)d_in[12];
    float* out = (float*)d_out;

    float* ws = (float*)d_ws;
    float*  t1 = ws;                       // 4096
    float*  t2 = ws + 4096;                // 4096
    float*  t3 = ws + 8192;                // 4096
    float*  t4 = ws + 12288;               // 1024
    float*  t5 = ws + 13312;               // 1024
    float2* p1 = (float2*)(ws + 14336);    // 1024 pairs
    float2* p2 = (float2*)(ws + 16384);    // 1024 pairs
    float2* p3 = (float2*)(ws + 18432);    // 1024 pairs
    float2* p4 = (float2*)(ws + 20480);    // 256 pairs
    float2* p5 = (float2*)(ws + 20992);    // 256 pairs

    const size_t lds = 4096 * sizeof(float);   // 16 KiB x-buffer

    k1<<<2048, 256, lds, stream>>>(W_I_H1, input_raw, W_H2_H1, h2_prev,
                                   t1, t2, p1, p2);
    k2<<<1280, 256, lds, stream>>>(t1, t2, p1, p2, g_H1, b_H1,
                                   W_H1_H2, W_H1_O, t3, t4, p3, p4);
    k3<<<256, 256, lds, stream>>>(t3, p3, g_H2, b_H2, W_H2_O, t5, p5);
    k4<<<1, 1024, 0, stream>>>(t4, t5, p4, p5, g_O, b_O, out);
}